// Round 16
// baseline (35.842 us; speedup 1.0000x reference)
//
#include <hip/hip_runtime.h>

typedef float f4 __attribute__((ext_vector_type(4)));
typedef _Float16 h2 __attribute__((ext_vector_type(2)));

#define Hdim 64
#define Wdim 64
#define Cdim 256
#define HW (Hdim * Wdim)

// v_dot2_f32_f16: d = a.x*b.x + a.y*b.y + c  (fp32 accumulate)
__device__ __forceinline__ float fdot2f(h2 a, h2 b, float c) {
#if __has_builtin(__builtin_amdgcn_fdot2)
    return __builtin_amdgcn_fdot2(a, b, c, false);
#else
    float d;
    asm("v_dot2_f32_f16 %0, %1, %2, %3" : "=v"(d) : "v"(a), "v"(b), "v"(c));
    return d;
#endif
}

// ---------------------------------------------------------------------------
// Pack kernel: x fp32 [b][c][h][w] -> ws half2 [b][c/2][h][w] = {x[2cp],x[2cp+1]}
// ---------------------------------------------------------------------------
__global__ __launch_bounds__(512) void pack_kernel(const float* __restrict__ x,
                                                   float* __restrict__ pw)
{
    const int tid = blockIdx.x * 512 + threadIdx.x;   // 0..524287
    const int wq = tid & 15;
    const int h  = (tid >> 4) & 63;
    const int cp = (tid >> 10) & 127;
    const int b  = tid >> 17;
    const float* s0 = x + ((size_t)b * Cdim + 2 * cp) * HW + h * 64 + wq * 4;
    f4 v0 = *(const f4*)s0;
    f4 v1 = *(const f4*)(s0 + HW);
    f4 ov;
    #pragma unroll
    for (int p = 0; p < 4; ++p) {
        h2 o;
        o[0] = (_Float16)v0[p];
        o[1] = (_Float16)v1[p];
        ov[p] = __builtin_bit_cast(float, o);
    }
    *(f4*)(pw + ((size_t)b * 128 + cp) * HW + h * 64 + wq * 4) = ov;
}

// ---------------------------------------------------------------------------
// KA: r13 champion's phase A + softmax, VERBATIM, ending in an attn store to
// ws instead of phase B. 512 blocks x 512 thr, XCD decode bid&7 -> (batch,
// 32-row band). attnG layout: [(b*64+h)*2+whalf][49][32] of (a,a) h2.
// ---------------------------------------------------------------------------
__global__ __launch_bounds__(512, 2) void ka_sim(const float* __restrict__ pwf,
                                                 float* __restrict__ attnG)
{
    const int bid = blockIdx.x;
    const int k   = bid & 7;
    const int seq = bid >> 3;            // 0..63
    const int b   = k >> 1;
    const int h   = (k & 1) * 32 + (seq >> 1);
    const int whalf = seq & 1;
    const int wbase = whalf * 32;        // w-half
    const int t = threadIdx.x;           // 0..511

    __shared__ float simRed[49][32];
    __shared__ float redBuf[7][32];
    __shared__ float psumBuf[7][32];

    const float* pw = pwf + (size_t)b * (128 * HW);   // h2 viewed as float

    // ---------------- Phase A: sim[k][w] over 128 channel-pairs ----------------
    // thread = (w4: bits 0..2, cp: bits 3..5, dy: wave). iter i: pair = i*8+cp.
    {
        const int w4 = t & 7;
        const int cp = (t >> 3) & 7;
        const int dy = t >> 6;           // wave-uniform; dy==7 idle
        const int lw0 = w4 * 4;
        const int w0g = wbase + lw0;

        if (dy < 7) {
            float sim[7][4];
            #pragma unroll
            for (int dx = 0; dx < 7; ++dx)
                #pragma unroll
                for (int p = 0; p < 4; ++p) sim[dx][p] = 0.f;

            const int row = h + dy - 3;
            if (row >= 0 && row < Hdim) {
                const bool hasL = (w0g != 0);
                const bool hasR = (w0g != 60);
                const float* xr = pw + (size_t)cp * HW + row * 64;
                const float* xc = pw + (size_t)cp * HW + h   * 64;
                for (int i = 0; i < 16; ++i) {
                    float fw[12];
                    if (hasL) {
                        f4 v = *(const f4*)(xr + w0g - 4);
                        fw[0]=v.x; fw[1]=v.y; fw[2]=v.z; fw[3]=v.w;
                    } else { fw[0]=0.f; fw[1]=0.f; fw[2]=0.f; fw[3]=0.f; }
                    {
                        f4 v = *(const f4*)(xr + w0g);
                        fw[4]=v.x; fw[5]=v.y; fw[6]=v.z; fw[7]=v.w;
                    }
                    if (hasR) {
                        f4 v = *(const f4*)(xr + w0g + 4);
                        fw[8]=v.x; fw[9]=v.y; fw[10]=v.z; fw[11]=v.w;
                    } else { fw[8]=0.f; fw[9]=0.f; fw[10]=0.f; fw[11]=0.f; }
                    f4 cen = *(const f4*)(xc + w0g);
                    h2 f2[12], cen2[4];
                    #pragma unroll
                    for (int j = 0; j < 12; ++j) f2[j] = __builtin_bit_cast(h2, fw[j]);
                    #pragma unroll
                    for (int p = 0; p < 4; ++p) cen2[p] = __builtin_bit_cast(h2, cen[p]);
                    #pragma unroll
                    for (int dx = 0; dx < 7; ++dx)
                        #pragma unroll
                        for (int p = 0; p < 4; ++p)
                            sim[dx][p] = fdot2f(cen2[p], f2[dx + p + 1], sim[dx][p]);
                    xr += 8 * HW;
                    xc += 8 * HW;
                }
            }
            // reduce over 8 channel partitions (lane bits 3..5)
            #pragma unroll
            for (int dx = 0; dx < 7; ++dx)
                #pragma unroll
                for (int p = 0; p < 4; ++p) {
                    float v = sim[dx][p];
                    v += __shfl_xor(v, 8);
                    v += __shfl_xor(v, 16);
                    v += __shfl_xor(v, 32);
                    sim[dx][p] = v;
                }
            if (cp == 0) {
                #pragma unroll
                for (int dx = 0; dx < 7; ++dx)
                    *(f4*)&simRed[dy * 7 + dx][lw0] = *(const f4*)sim[dx];
            }
        }
    }
    __syncthreads();

    // ---------------- Softmax over k=49; attn (a,a) h2 -> global ws ----------------
    {
        const int w  = t & 31;
        const int kc = t >> 5;    // 0..15; kc<7 active
        float sred[7], e[7];
        if (kc < 7) {
            float lmax = -3.0e38f;
            #pragma unroll
            for (int jj = 0; jj < 7; ++jj) {
                float s = simRed[kc * 7 + jj][w];
                sred[jj] = s;
                lmax = fmaxf(lmax, s);
            }
            redBuf[kc][w] = lmax;
        }
        __syncthreads();
        if (kc < 7) {
            float m = redBuf[0][w];
            #pragma unroll
            for (int q = 1; q < 7; ++q) m = fmaxf(m, redBuf[q][w]);
            float ps = 0.f;
            #pragma unroll
            for (int jj = 0; jj < 7; ++jj) {
                e[jj] = __expf(sred[jj] - m);
                ps += e[jj];
            }
            psumBuf[kc][w] = ps;
        }
        __syncthreads();
        if (kc < 7) {
            float l = psumBuf[0][w];
            #pragma unroll
            for (int q = 1; q < 7; ++q) l += psumBuf[q][w];
            float rinv = 1.0f / l;
            float* ag = attnG + (size_t)(((b * 64 + h) * 2 + whalf) * 49) * 32;
            #pragma unroll
            for (int jj = 0; jj < 7; ++jj) {
                _Float16 ah = (_Float16)(e[jj] * rinv);
                h2 av; av[0] = ah; av[1] = ah;
                ag[(kc * 7 + jj) * 32 + w] = __builtin_bit_cast(float, av);
            }
        }
    }
}

// ---------------------------------------------------------------------------
// KB: phase B only, high occupancy. 1024 blocks x 512 thr:
// (b, h, whalf, chalf); 1 channel-pair/thread, 7 dy x 3 window loads,
// v_pk_fma_f16, attn staged into LDS (broadcast reads, conflict-free).
// Register-lean (~50 VGPR) -> 8 waves/SIMD target.
// ---------------------------------------------------------------------------
__global__ __launch_bounds__(512) void kb_out(const float* __restrict__ pwf,
                                              const float* __restrict__ attnG,
                                              float* __restrict__ out)
{
    const int bid = blockIdx.x;          // 0..1023
    const int k   = bid & 7;
    const int seq = bid >> 3;            // 0..127
    const int b   = k >> 1;
    const int h   = (k & 1) * 32 + (seq >> 2);
    const int whalf = (seq >> 1) & 1;
    const int chalf = seq & 1;
    const int wbase = whalf * 32;
    const int t = threadIdx.x;           // 0..511

    __shared__ __align__(16) h2 attnH[49][32];

    const float* pw = pwf + (size_t)b * (128 * HW);

    // stage attn (49x32 h2 = 6272B) : 392 f4 reads
    {
        const float* ag = attnG + (size_t)(((b * 64 + h) * 2 + whalf) * 49) * 32;
        if (t < 392) {
            const int kk = t >> 3;
            const int wq = t & 7;
            *(f4*)&attnH[kk][wq * 4] = *(const f4*)(ag + kk * 32 + wq * 4);
        }
    }
    __syncthreads();

    // phase B: 1 pair/thread
    {
        const int w4 = t & 7;
        const int ci = t >> 3;           // 0..63
        const int pair = chalf * 64 + ci;
        const int lw0 = w4 * 4;
        const int w0g = wbase + lw0;
        const bool hasL = (w0g != 0);
        const bool hasR = (w0g != 60);

        h2 acc2[4];
        #pragma unroll
        for (int p = 0; p < 4; ++p) { acc2[p][0] = (_Float16)0; acc2[p][1] = (_Float16)0; }

        for (int dy = 0; dy < 7; ++dy) {
            const int row = h + dy - 3;
            if (row < 0 || row >= Hdim) continue;   // block-uniform
            h2 a2[7][4];
            #pragma unroll
            for (int dx = 0; dx < 7; ++dx) {
                f4 v = *(const f4*)&attnH[dy * 7 + dx][lw0];
                #pragma unroll
                for (int p = 0; p < 4; ++p) a2[dx][p] = __builtin_bit_cast(h2, v[p]);
            }
            const float* xr = pw + (size_t)pair * HW + row * 64;
            float fw[12];
            if (hasL) {
                f4 v = *(const f4*)(xr + w0g - 4);
                fw[0]=v.x; fw[1]=v.y; fw[2]=v.z; fw[3]=v.w;
            } else { fw[0]=0.f; fw[1]=0.f; fw[2]=0.f; fw[3]=0.f; }
            {
                f4 v = *(const f4*)(xr + w0g);
                fw[4]=v.x; fw[5]=v.y; fw[6]=v.z; fw[7]=v.w;
            }
            if (hasR) {
                f4 v = *(const f4*)(xr + w0g + 4);
                fw[8]=v.x; fw[9]=v.y; fw[10]=v.z; fw[11]=v.w;
            } else { fw[8]=0.f; fw[9]=0.f; fw[10]=0.f; fw[11]=0.f; }
            h2 f2[12];
            #pragma unroll
            for (int j = 0; j < 12; ++j) f2[j] = __builtin_bit_cast(h2, fw[j]);
            #pragma unroll
            for (int dx = 0; dx < 7; ++dx)
                #pragma unroll
                for (int p = 0; p < 4; ++p)
                    acc2[p] += a2[dx][p] * f2[dx + p + 1];   // v_pk_fma_f16
        }

        float* ob = out + (size_t)b * (Cdim * HW) + h * Wdim + w0g;
        f4 o0, o1;
        #pragma unroll
        for (int p = 0; p < 4; ++p) {
            o0[p] = (float)acc2[p][0];
            o1[p] = (float)acc2[p][1];
        }
        *(f4*)(ob + (size_t)(2 * pair) * HW)     = o0;
        *(f4*)(ob + (size_t)(2 * pair + 1) * HW) = o1;
    }
}

// ---------------------------------------------------------------------------
// Fallback: r11 fp32 champion (40.0us) if ws is too small.
// ---------------------------------------------------------------------------
__global__ __launch_bounds__(512, 2) void selfattn_fb(const float* __restrict__ x,
                                                      float* __restrict__ out)
{
    const int bid = blockIdx.x;
    const int k   = bid & 7;
    const int seq = bid >> 3;
    const int b   = k >> 1;
    const int h   = (k & 1) * 32 + (seq >> 1);
    const int wbase = (seq & 1) * 32;
    const int t = threadIdx.x;

    __shared__ float simRed[49][32];
    __shared__ float attnBuf[49][32];
    __shared__ float redBuf[7][32];
    __shared__ float psumBuf[7][32];

    const float* xb = x + (size_t)b * (Cdim * HW);

    {
        const int w4 = t & 7;
        const int cp = (t >> 3) & 7;
        const int dy = t >> 6;
        const int lw0 = w4 * 4;
        const int w0g = wbase + lw0;

        if (dy < 7) {
            float sim[7][4];
            #pragma unroll
            for (int dx = 0; dx < 7; ++dx)
                #pragma unroll
                for (int p = 0; p < 4; ++p) sim[dx][p] = 0.f;

            const int row = h + dy - 3;
            if (row >= 0 && row < Hdim) {
                const bool hasL = (w0g != 0);
                const bool hasR = (w0g != 60);
                const float* xrA = xb + (size_t)cp * HW + row * Wdim;
                const float* xcA = xb + (size_t)cp * HW + h   * Wdim;
                const float* xrB = xrA + (size_t)128 * HW;
                const float* xcB = xcA + (size_t)128 * HW;
                #pragma unroll 2
                for (int i = 0; i < 16; ++i) {
                    float fA[12], fB[12];
                    if (hasL) {
                        f4 v = *(const f4*)(xrA + w0g - 4);
                        fA[0]=v.x; fA[1]=v.y; fA[2]=v.z; fA[3]=v.w;
                    } else { fA[0]=0.f; fA[1]=0.f; fA[2]=0.f; fA[3]=0.f; }
                    {
                        f4 v = *(const f4*)(xrA + w0g);
                        fA[4]=v.x; fA[5]=v.y; fA[6]=v.z; fA[7]=v.w;
                    }
                    if (hasR) {
                        f4 v = *(const f4*)(xrA + w0g + 4);
                        fA[8]=v.x; fA[9]=v.y; fA[10]=v.z; fA[11]=v.w;
                    } else { fA[8]=0.f; fA[9]=0.f; fA[10]=0.f; fA[11]=0.f; }
                    if (hasL) {
                        f4 v = *(const f4*)(xrB + w0g - 4);
                        fB[0]=v.x; fB[1]=v.y; fB[2]=v.z; fB[3]=v.w;
                    } else { fB[0]=0.f; fB[1]=0.f; fB[2]=0.f; fB[3]=0.f; }
                    {
                        f4 v = *(const f4*)(xrB + w0g);
                        fB[4]=v.x; fB[5]=v.y; fB[6]=v.z; fB[7]=v.w;
                    }
                    if (hasR) {
                        f4 v = *(const f4*)(xrB + w0g + 4);
                        fB[8]=v.x; fB[9]=v.y; fB[10]=v.z; fB[11]=v.w;
                    } else { fB[8]=0.f; fB[9]=0.f; fB[10]=0.f; fB[11]=0.f; }
                    f4 cenA = *(const f4*)(xcA + w0g);
                    f4 cenB = *(const f4*)(xcB + w0g);
                    #pragma unroll
                    for (int dx = 0; dx < 7; ++dx)
                        #pragma unroll
                        for (int p = 0; p < 4; ++p)
                            sim[dx][p] += cenA[p] * fA[dx + p + 1]
                                        + cenB[p] * fB[dx + p + 1];
                    xrA += 8 * HW;  xcA += 8 * HW;
                    xrB += 8 * HW;  xcB += 8 * HW;
                }
            }
            #pragma unroll
            for (int dx = 0; dx < 7; ++dx)
                #pragma unroll
                for (int p = 0; p < 4; ++p) {
                    float v = sim[dx][p];
                    v += __shfl_xor(v, 8);
                    v += __shfl_xor(v, 16);
                    v += __shfl_xor(v, 32);
                    sim[dx][p] = v;
                }
            if (cp == 0) {
                #pragma unroll
                for (int dx = 0; dx < 7; ++dx)
                    *(f4*)&simRed[dy * 7 + dx][lw0] = *(const f4*)sim[dx];
            }
        }
    }
    __syncthreads();

    {
        const int w  = t & 31;
        const int kc = t >> 5;
        float sred[7], e[7];
        if (kc < 7) {
            float lmax = -3.0e38f;
            #pragma unroll
            for (int jj = 0; jj < 7; ++jj) {
                float s = simRed[kc * 7 + jj][w];
                sred[jj] = s;
                lmax = fmaxf(lmax, s);
            }
            redBuf[kc][w] = lmax;
        }
        __syncthreads();
        if (kc < 7) {
            float m = redBuf[0][w];
            #pragma unroll
            for (int q = 1; q < 7; ++q) m = fmaxf(m, redBuf[q][w]);
            float ps = 0.f;
            #pragma unroll
            for (int jj = 0; jj < 7; ++jj) {
                e[jj] = __expf(sred[jj] - m);
                ps += e[jj];
            }
            psumBuf[kc][w] = ps;
        }
        __syncthreads();
        if (kc < 7) {
            float l = psumBuf[0][w];
            #pragma unroll
            for (int q = 1; q < 7; ++q) l += psumBuf[q][w];
            float rinv = 1.0f / l;
            #pragma unroll
            for (int jj = 0; jj < 7; ++jj)
                attnBuf[kc * 7 + jj][w] = e[jj] * rinv;
        }
    }
    __syncthreads();

    {
        const int w4 = t & 7;
        const int ci = t >> 3;
        const int lw0 = w4 * 4;
        const int w0g = wbase + lw0;
        const int c0 = ci * 4;
        const bool hasL = (w0g != 0);
        const bool hasR = (w0g != 60);

        float acc[4][4];
        #pragma unroll
        for (int ch = 0; ch < 4; ++ch)
            #pragma unroll
            for (int p = 0; p < 4; ++p) acc[ch][p] = 0.f;

        for (int dy = 0; dy < 7; ++dy) {
            const int row = h + dy - 3;
            if (row < 0 || row >= Hdim) continue;
            float a[7][4];
            #pragma unroll
            for (int dx = 0; dx < 7; ++dx) {
                f4 v = *(const f4*)&attnBuf[dy * 7 + dx][lw0];
                a[dx][0]=v.x; a[dx][1]=v.y; a[dx][2]=v.z; a[dx][3]=v.w;
            }
            const float* xr = xb + (size_t)c0 * HW + row * Wdim;
            #pragma unroll
            for (int ch = 0; ch < 4; ++ch) {
                float fw[12];
                if (hasL) {
                    f4 v = *(const f4*)(xr + w0g - 4);
                    fw[0]=v.x; fw[1]=v.y; fw[2]=v.z; fw[3]=v.w;
                } else { fw[0]=0.f; fw[1]=0.f; fw[2]=0.f; fw[3]=0.f; }
                {
                    f4 v = *(const f4*)(xr + w0g);
                    fw[4]=v.x; fw[5]=v.y; fw[6]=v.z; fw[7]=v.w;
                }
                if (hasR) {
                    f4 v = *(const f4*)(xr + w0g + 4);
                    fw[8]=v.x; fw[9]=v.y; fw[10]=v.z; fw[11]=v.w;
                } else { fw[8]=0.f; fw[9]=0.f; fw[10]=0.f; fw[11]=0.f; }
                #pragma unroll
                for (int dx = 0; dx < 7; ++dx)
                    #pragma unroll
                    for (int p = 0; p < 4; ++p)
                        acc[ch][p] += a[dx][p] * fw[dx + p + 1];
                xr += HW;
            }
        }

        float* ob = out + (size_t)b * (Cdim * HW) + h * Wdim + wbase;
        #pragma unroll
        for (int ch = 0; ch < 4; ++ch)
            *(f4*)(ob + (size_t)(c0 + ch) * HW + lw0) = *(const f4*)acc[ch];
    }
}

extern "C" void kernel_launch(void* const* d_in, const int* in_sizes, int n_in,
                              void* d_out, int out_size, void* d_ws, size_t ws_size,
                              hipStream_t stream)
{
    const float* x = (const float*)d_in[0];
    float* out = (float*)d_out;
    const size_t pwFloats = (size_t)4 * 128 * HW;           // 8 MB packed half2
    const size_t attnFloats = (size_t)512 * 49 * 32;        // 3.2 MB attn
    const size_t need = (pwFloats + attnFloats) * 4;
    if (ws_size >= need) {
        float* pw = (float*)d_ws;
        float* attnG = pw + pwFloats;
        pack_kernel<<<dim3(1024), 512, 0, stream>>>(x, pw);
        ka_sim<<<dim3(512), 512, 0, stream>>>(pw, attnG);
        kb_out<<<dim3(1024), 512, 0, stream>>>(pw, attnG, out);
    } else {
        selfattn_fb<<<dim3(512), 512, 0, stream>>>(x, out);
    }
}

// Round 17
// 33.764 us; speedup vs baseline: 1.0615x; 1.0615x over previous
//
#include <hip/hip_runtime.h>

typedef float f4 __attribute__((ext_vector_type(4)));
typedef _Float16 h2 __attribute__((ext_vector_type(2)));

#define Hdim 64
#define Wdim 64
#define Cdim 256
#define HW (Hdim * Wdim)

// v_dot2_f32_f16: d = a.x*b.x + a.y*b.y + c  (fp32 accumulate)
__device__ __forceinline__ float fdot2f(h2 a, h2 b, float c) {
#if __has_builtin(__builtin_amdgcn_fdot2)
    return __builtin_amdgcn_fdot2(a, b, c, false);
#else
    float d;
    asm("v_dot2_f32_f16 %0, %1, %2, %3" : "=v"(d) : "v"(a), "v"(b), "v"(c));
    return d;
#endif
}

// ---------------------------------------------------------------------------
// Pack kernel: x fp32 [b][c][h][w] -> ws half2 [b][c/2][h][w] = {x[2cp],x[2cp+1]}
// ---------------------------------------------------------------------------
__global__ __launch_bounds__(512) void pack_kernel(const float* __restrict__ x,
                                                   float* __restrict__ pw)
{
    const int tid = blockIdx.x * 512 + threadIdx.x;   // 0..524287
    const int wq = tid & 15;
    const int h  = (tid >> 4) & 63;
    const int cp = (tid >> 10) & 127;
    const int b  = tid >> 17;
    const float* s0 = x + ((size_t)b * Cdim + 2 * cp) * HW + h * 64 + wq * 4;
    f4 v0 = *(const f4*)s0;
    f4 v1 = *(const f4*)(s0 + HW);
    f4 ov;
    #pragma unroll
    for (int p = 0; p < 4; ++p) {
        h2 o;
        o[0] = (_Float16)v0[p];
        o[1] = (_Float16)v1[p];
        ov[p] = __builtin_bit_cast(float, o);
    }
    *(f4*)(pw + ((size_t)b * 128 + cp) * HW + h * 64 + wq * 4) = ov;
}

// ---------------------------------------------------------------------------
// Main kernel: r13 champion (33.2us total) + window-via-shuffle in phase A.
// Lane layout: w4 = lane bits 0..2, cp = bits 3..5 -> lane-1's middle f4 IS
// this lane's left f4 (same cp, w4-1), lane+1's middle IS the right f4.
// Phase A per iter: 2 global loads (middle + cen) + 8 __shfl (ds_bpermute)
// + exec-masked edge loads on w4==0 / w4==7 lanes, vs 4 global loads in r13.
// ~1.9x fewer phase-A global bytes; values bit-identical.
// Geometry unchanged: 512 blocks (b,h,w-half) x 512 thr, XCD decode bid&7 ->
// (batch, 32-row band), launch_bounds(512,2) (cap 128, proven no-spill).
// ---------------------------------------------------------------------------
__global__ __launch_bounds__(512, 2) void selfattn_f16(const float* __restrict__ pwf,
                                                       float* __restrict__ out)
{
    const int bid = blockIdx.x;
    const int k   = bid & 7;
    const int seq = bid >> 3;            // 0..63
    const int b   = k >> 1;
    const int h   = (k & 1) * 32 + (seq >> 1);
    const int wbase = (seq & 1) * 32;    // w-half
    const int t = threadIdx.x;           // 0..511

    __shared__ float simRed[49][32];
    __shared__ __align__(16) h2 attnH[49][32];   // (a,a) packed
    __shared__ float redBuf[7][32];
    __shared__ float psumBuf[7][32];

    const float* pw = pwf + (size_t)b * (128 * HW);   // h2 elements viewed as float

    // ---------------- Phase A: sim[k][w] over 128 channel-pairs ----------------
    // thread = (w4: bits 0..2, cp: bits 3..5, dy: wave). iter i: pair = i*8+cp.
    {
        const int w4 = t & 7;
        const int cp = (t >> 3) & 7;
        const int dy = t >> 6;           // wave-uniform; dy==7 idle
        const int lane = t & 63;
        const int laneL = (lane + 63) & 63;
        const int laneR = (lane + 1) & 63;
        const int lw0 = w4 * 4;
        const int w0g = wbase + lw0;

        if (dy < 7) {
            float sim[7][4];
            #pragma unroll
            for (int dx = 0; dx < 7; ++dx)
                #pragma unroll
                for (int p = 0; p < 4; ++p) sim[dx][p] = 0.f;

            const int row = h + dy - 3;
            if (row >= 0 && row < Hdim) {
                const float* xr = pw + (size_t)cp * HW + row * 64;
                const float* xc = pw + (size_t)cp * HW + h   * 64;
                for (int i = 0; i < 16; ++i) {
                    f4 mid = *(const f4*)(xr + w0g);
                    f4 lf, rf;
                    #pragma unroll
                    for (int p = 0; p < 4; ++p) lf[p] = __shfl(mid[p], laneL);
                    #pragma unroll
                    for (int p = 0; p < 4; ++p) rf[p] = __shfl(mid[p], laneR);
                    if (w4 == 0) {
                        if (wbase != 0) {
                            lf = *(const f4*)(xr + w0g - 4);
                        } else {
                            lf[0]=0.f; lf[1]=0.f; lf[2]=0.f; lf[3]=0.f;
                        }
                    }
                    if (w4 == 7) {
                        if (wbase == 0) {
                            rf = *(const f4*)(xr + w0g + 4);
                        } else {
                            rf[0]=0.f; rf[1]=0.f; rf[2]=0.f; rf[3]=0.f;
                        }
                    }
                    f4 cen = *(const f4*)(xc + w0g);
                    float fw[12];
                    fw[0]=lf[0];  fw[1]=lf[1];  fw[2]=lf[2];  fw[3]=lf[3];
                    fw[4]=mid[0]; fw[5]=mid[1]; fw[6]=mid[2]; fw[7]=mid[3];
                    fw[8]=rf[0];  fw[9]=rf[1];  fw[10]=rf[2]; fw[11]=rf[3];
                    h2 f2[12], cen2[4];
                    #pragma unroll
                    for (int j = 0; j < 12; ++j) f2[j] = __builtin_bit_cast(h2, fw[j]);
                    #pragma unroll
                    for (int p = 0; p < 4; ++p) cen2[p] = __builtin_bit_cast(h2, cen[p]);
                    #pragma unroll
                    for (int dx = 0; dx < 7; ++dx)
                        #pragma unroll
                        for (int p = 0; p < 4; ++p)
                            sim[dx][p] = fdot2f(cen2[p], f2[dx + p + 1], sim[dx][p]);
                    xr += 8 * HW;
                    xc += 8 * HW;
                }
            }
            // reduce over 8 channel partitions (lane bits 3..5)
            #pragma unroll
            for (int dx = 0; dx < 7; ++dx)
                #pragma unroll
                for (int p = 0; p < 4; ++p) {
                    float v = sim[dx][p];
                    v += __shfl_xor(v, 8);
                    v += __shfl_xor(v, 16);
                    v += __shfl_xor(v, 32);
                    sim[dx][p] = v;
                }
            if (cp == 0) {
                #pragma unroll
                for (int dx = 0; dx < 7; ++dx)
                    *(f4*)&simRed[dy * 7 + dx][lw0] = *(const f4*)sim[dx];
            }
        }
    }
    __syncthreads();

    // ---------------- Softmax over k=49; attn stored as (a,a) half2 ----------------
    {
        const int w  = t & 31;
        const int kc = t >> 5;    // 0..15; kc<7 active
        float sred[7], e[7];
        if (kc < 7) {
            float lmax = -3.0e38f;
            #pragma unroll
            for (int jj = 0; jj < 7; ++jj) {
                float s = simRed[kc * 7 + jj][w];
                sred[jj] = s;
                lmax = fmaxf(lmax, s);
            }
            redBuf[kc][w] = lmax;
        }
        __syncthreads();
        if (kc < 7) {
            float m = redBuf[0][w];
            #pragma unroll
            for (int q = 1; q < 7; ++q) m = fmaxf(m, redBuf[q][w]);
            float ps = 0.f;
            #pragma unroll
            for (int jj = 0; jj < 7; ++jj) {
                e[jj] = __expf(sred[jj] - m);
                ps += e[jj];
            }
            psumBuf[kc][w] = ps;
        }
        __syncthreads();
        if (kc < 7) {
            float l = psumBuf[0][w];
            #pragma unroll
            for (int q = 1; q < 7; ++q) l += psumBuf[q][w];
            float rinv = 1.0f / l;
            #pragma unroll
            for (int jj = 0; jj < 7; ++jj) {
                _Float16 ah = (_Float16)(e[jj] * rinv);
                h2 av; av[0] = ah; av[1] = ah;
                attnH[kc * 7 + jj][w] = av;
            }
        }
    }
    __syncthreads();

    // ---------------- Phase B: out via v_pk_fma_f16 ----------------
    // thread = (w4: bits 0..2, ci: bits 3..8) -> pairs 2ci,2ci+1 = channels 4ci..4ci+3
    {
        const int w4 = t & 7;
        const int ci = t >> 3;           // 0..63
        const int lw0 = w4 * 4;
        const int w0g = wbase + lw0;
        const bool hasL = (w0g != 0);
        const bool hasR = (w0g != 60);

        h2 acc2[2][4];
        #pragma unroll
        for (int pr = 0; pr < 2; ++pr)
            #pragma unroll
            for (int p = 0; p < 4; ++p) { acc2[pr][p][0] = (_Float16)0; acc2[pr][p][1] = (_Float16)0; }

        for (int dy = 0; dy < 7; ++dy) {
            const int row = h + dy - 3;
            if (row < 0 || row >= Hdim) continue;   // block-uniform
            h2 a2[7][4];
            #pragma unroll
            for (int dx = 0; dx < 7; ++dx) {
                f4 v = *(const f4*)&attnH[dy * 7 + dx][lw0];
                #pragma unroll
                for (int p = 0; p < 4; ++p) a2[dx][p] = __builtin_bit_cast(h2, v[p]);
            }
            #pragma unroll
            for (int pr = 0; pr < 2; ++pr) {
                const float* xr = pw + (size_t)(2 * ci + pr) * HW + row * 64;
                float fw[12];
                if (hasL) {
                    f4 v = *(const f4*)(xr + w0g - 4);
                    fw[0]=v.x; fw[1]=v.y; fw[2]=v.z; fw[3]=v.w;
                } else { fw[0]=0.f; fw[1]=0.f; fw[2]=0.f; fw[3]=0.f; }
                {
                    f4 v = *(const f4*)(xr + w0g);
                    fw[4]=v.x; fw[5]=v.y; fw[6]=v.z; fw[7]=v.w;
                }
                if (hasR) {
                    f4 v = *(const f4*)(xr + w0g + 4);
                    fw[8]=v.x; fw[9]=v.y; fw[10]=v.z; fw[11]=v.w;
                } else { fw[8]=0.f; fw[9]=0.f; fw[10]=0.f; fw[11]=0.f; }
                h2 f2[12];
                #pragma unroll
                for (int j = 0; j < 12; ++j) f2[j] = __builtin_bit_cast(h2, fw[j]);
                #pragma unroll
                for (int dx = 0; dx < 7; ++dx)
                    #pragma unroll
                    for (int p = 0; p < 4; ++p)
                        acc2[pr][p] += a2[dx][p] * f2[dx + p + 1];   // v_pk_fma_f16
            }
        }

        float* ob = out + (size_t)b * (Cdim * HW) + h * Wdim + w0g;
        #pragma unroll
        for (int pr = 0; pr < 2; ++pr) {
            f4 o0, o1;
            #pragma unroll
            for (int p = 0; p < 4; ++p) {
                o0[p] = (float)acc2[pr][p][0];
                o1[p] = (float)acc2[pr][p][1];
            }
            const int c0 = 4 * ci + 2 * pr;
            *(f4*)(ob + (size_t)c0 * HW)       = o0;
            *(f4*)(ob + (size_t)(c0 + 1) * HW) = o1;
        }
    }
}

// ---------------------------------------------------------------------------
// Fallback: r11 fp32 champion (40.0us) if ws is too small for the packed copy.
// ---------------------------------------------------------------------------
__global__ __launch_bounds__(512, 2) void selfattn_fb(const float* __restrict__ x,
                                                      float* __restrict__ out)
{
    const int bid = blockIdx.x;
    const int k   = bid & 7;
    const int seq = bid >> 3;
    const int b   = k >> 1;
    const int h   = (k & 1) * 32 + (seq >> 1);
    const int wbase = (seq & 1) * 32;
    const int t = threadIdx.x;

    __shared__ float simRed[49][32];
    __shared__ float attnBuf[49][32];
    __shared__ float redBuf[7][32];
    __shared__ float psumBuf[7][32];

    const float* xb = x + (size_t)b * (Cdim * HW);

    {
        const int w4 = t & 7;
        const int cp = (t >> 3) & 7;
        const int dy = t >> 6;
        const int lw0 = w4 * 4;
        const int w0g = wbase + lw0;

        if (dy < 7) {
            float sim[7][4];
            #pragma unroll
            for (int dx = 0; dx < 7; ++dx)
                #pragma unroll
                for (int p = 0; p < 4; ++p) sim[dx][p] = 0.f;

            const int row = h + dy - 3;
            if (row >= 0 && row < Hdim) {
                const bool hasL = (w0g != 0);
                const bool hasR = (w0g != 60);
                const float* xrA = xb + (size_t)cp * HW + row * Wdim;
                const float* xcA = xb + (size_t)cp * HW + h   * Wdim;
                const float* xrB = xrA + (size_t)128 * HW;
                const float* xcB = xcA + (size_t)128 * HW;
                #pragma unroll 2
                for (int i = 0; i < 16; ++i) {
                    float fA[12], fB[12];
                    if (hasL) {
                        f4 v = *(const f4*)(xrA + w0g - 4);
                        fA[0]=v.x; fA[1]=v.y; fA[2]=v.z; fA[3]=v.w;
                    } else { fA[0]=0.f; fA[1]=0.f; fA[2]=0.f; fA[3]=0.f; }
                    {
                        f4 v = *(const f4*)(xrA + w0g);
                        fA[4]=v.x; fA[5]=v.y; fA[6]=v.z; fA[7]=v.w;
                    }
                    if (hasR) {
                        f4 v = *(const f4*)(xrA + w0g + 4);
                        fA[8]=v.x; fA[9]=v.y; fA[10]=v.z; fA[11]=v.w;
                    } else { fA[8]=0.f; fA[9]=0.f; fA[10]=0.f; fA[11]=0.f; }
                    if (hasL) {
                        f4 v = *(const f4*)(xrB + w0g - 4);
                        fB[0]=v.x; fB[1]=v.y; fB[2]=v.z; fB[3]=v.w;
                    } else { fB[0]=0.f; fB[1]=0.f; fB[2]=0.f; fB[3]=0.f; }
                    {
                        f4 v = *(const f4*)(xrB + w0g);
                        fB[4]=v.x; fB[5]=v.y; fB[6]=v.z; fB[7]=v.w;
                    }
                    if (hasR) {
                        f4 v = *(const f4*)(xrB + w0g + 4);
                        fB[8]=v.x; fB[9]=v.y; fB[10]=v.z; fB[11]=v.w;
                    } else { fB[8]=0.f; fB[9]=0.f; fB[10]=0.f; fB[11]=0.f; }
                    f4 cenA = *(const f4*)(xcA + w0g);
                    f4 cenB = *(const f4*)(xcB + w0g);
                    #pragma unroll
                    for (int dx = 0; dx < 7; ++dx)
                        #pragma unroll
                        for (int p = 0; p < 4; ++p)
                            sim[dx][p] += cenA[p] * fA[dx + p + 1]
                                        + cenB[p] * fB[dx + p + 1];
                    xrA += 8 * HW;  xcA += 8 * HW;
                    xrB += 8 * HW;  xcB += 8 * HW;
                }
            }
            #pragma unroll
            for (int dx = 0; dx < 7; ++dx)
                #pragma unroll
                for (int p = 0; p < 4; ++p) {
                    float v = sim[dx][p];
                    v += __shfl_xor(v, 8);
                    v += __shfl_xor(v, 16);
                    v += __shfl_xor(v, 32);
                    sim[dx][p] = v;
                }
            if (cp == 0) {
                #pragma unroll
                for (int dx = 0; dx < 7; ++dx)
                    *(f4*)&simRed[dy * 7 + dx][lw0] = *(const f4*)sim[dx];
            }
        }
    }
    __syncthreads();

    {
        const int w  = t & 31;
        const int kc = t >> 5;
        float sred[7], e[7];
        if (kc < 7) {
            float lmax = -3.0e38f;
            #pragma unroll
            for (int jj = 0; jj < 7; ++jj) {
                float s = simRed[kc * 7 + jj][w];
                sred[jj] = s;
                lmax = fmaxf(lmax, s);
            }
            redBuf[kc][w] = lmax;
        }
        __syncthreads();
        if (kc < 7) {
            float m = redBuf[0][w];
            #pragma unroll
            for (int q = 1; q < 7; ++q) m = fmaxf(m, redBuf[q][w]);
            float ps = 0.f;
            #pragma unroll
            for (int jj = 0; jj < 7; ++jj) {
                e[jj] = __expf(sred[jj] - m);
                ps += e[jj];
            }
            psumBuf[kc][w] = ps;
        }
        __syncthreads();
        if (kc < 7) {
            float l = psumBuf[0][w];
            #pragma unroll
            for (int q = 1; q < 7; ++q) l += psumBuf[q][w];
            float rinv = 1.0f / l;
            #pragma unroll
            for (int jj = 0; jj < 7; ++jj)
                attnBuf[kc * 7 + jj][w] = e[jj] * rinv;
        }
    }
    __syncthreads();

    {
        const int w4 = t & 7;
        const int ci = t >> 3;
        const int lw0 = w4 * 4;
        const int w0g = wbase + lw0;
        const int c0 = ci * 4;
        const bool hasL = (w0g != 0);
        const bool hasR = (w0g != 60);

        float acc[4][4];
        #pragma unroll
        for (int ch = 0; ch < 4; ++ch)
            #pragma unroll
            for (int p = 0; p < 4; ++p) acc[ch][p] = 0.f;

        for (int dy = 0; dy < 7; ++dy) {
            const int row = h + dy - 3;
            if (row < 0 || row >= Hdim) continue;
            float a[7][4];
            #pragma unroll
            for (int dx = 0; dx < 7; ++dx) {
                f4 v = *(const f4*)&attnBuf[dy * 7 + dx][lw0];
                a[dx][0]=v.x; a[dx][1]=v.y; a[dx][2]=v.z; a[dx][3]=v.w;
            }
            const float* xr = xb + (size_t)c0 * HW + row * Wdim;
            #pragma unroll
            for (int ch = 0; ch < 4; ++ch) {
                float fw[12];
                if (hasL) {
                    f4 v = *(const f4*)(xr + w0g - 4);
                    fw[0]=v.x; fw[1]=v.y; fw[2]=v.z; fw[3]=v.w;
                } else { fw[0]=0.f; fw[1]=0.f; fw[2]=0.f; fw[3]=0.f; }
                {
                    f4 v = *(const f4*)(xr + w0g);
                    fw[4]=v.x; fw[5]=v.y; fw[6]=v.z; fw[7]=v.w;
                }
                if (hasR) {
                    f4 v = *(const f4*)(xr + w0g + 4);
                    fw[8]=v.x; fw[9]=v.y; fw[10]=v.z; fw[11]=v.w;
                } else { fw[8]=0.f; fw[9]=0.f; fw[10]=0.f; fw[11]=0.f; }
                #pragma unroll
                for (int dx = 0; dx < 7; ++dx)
                    #pragma unroll
                    for (int p = 0; p < 4; ++p)
                        acc[ch][p] += a[dx][p] * fw[dx + p + 1];
                xr += HW;
            }
        }

        float* ob = out + (size_t)b * (Cdim * HW) + h * Wdim + wbase;
        #pragma unroll
        for (int ch = 0; ch < 4; ++ch)
            *(f4*)(ob + (size_t)(c0 + ch) * HW + lw0) = *(const f4*)acc[ch];
    }
}

extern "C" void kernel_launch(void* const* d_in, const int* in_sizes, int n_in,
                              void* d_out, int out_size, void* d_ws, size_t ws_size,
                              hipStream_t stream)
{
    const float* x = (const float*)d_in[0];
    float* out = (float*)d_out;
    const size_t need = (size_t)4 * 128 * HW * 4;   // 8 MB packed half2
    if (ws_size >= need) {
        float* pw = (float*)d_ws;
        pack_kernel<<<dim3(1024), 512, 0, stream>>>(x, pw);
        selfattn_f16<<<dim3(512), 512, 0, stream>>>(pw, out);
    } else {
        selfattn_fb<<<dim3(512), 512, 0, stream>>>(x, out);
    }
}

// Round 18
// 33.524 us; speedup vs baseline: 1.0691x; 1.0072x over previous
//
#include <hip/hip_runtime.h>

typedef float f4 __attribute__((ext_vector_type(4)));
typedef _Float16 h2 __attribute__((ext_vector_type(2)));

#define Hdim 64
#define Wdim 64
#define Cdim 256
#define HW (Hdim * Wdim)

// v_dot2_f32_f16: d = a.x*b.x + a.y*b.y + c  (fp32 accumulate)
__device__ __forceinline__ float fdot2f(h2 a, h2 b, float c) {
#if __has_builtin(__builtin_amdgcn_fdot2)
    return __builtin_amdgcn_fdot2(a, b, c, false);
#else
    float d;
    asm("v_dot2_f32_f16 %0, %1, %2, %3" : "=v"(d) : "v"(a), "v"(b), "v"(c));
    return d;
#endif
}

// ---------------------------------------------------------------------------
// Pack kernel: x fp32 [b][c][h][w] -> ws half2 [b][c/2][h][w] = {x[2cp],x[2cp+1]}
// ---------------------------------------------------------------------------
__global__ __launch_bounds__(512) void pack_kernel(const float* __restrict__ x,
                                                   float* __restrict__ pw)
{
    const int tid = blockIdx.x * 512 + threadIdx.x;   // 0..524287
    const int wq = tid & 15;
    const int h  = (tid >> 4) & 63;
    const int cp = (tid >> 10) & 127;
    const int b  = tid >> 17;
    const float* s0 = x + ((size_t)b * Cdim + 2 * cp) * HW + h * 64 + wq * 4;
    f4 v0 = *(const f4*)s0;
    f4 v1 = *(const f4*)(s0 + HW);
    f4 ov;
    #pragma unroll
    for (int p = 0; p < 4; ++p) {
        h2 o;
        o[0] = (_Float16)v0[p];
        o[1] = (_Float16)v1[p];
        ov[p] = __builtin_bit_cast(float, o);
    }
    *(f4*)(pw + ((size_t)b * 128 + cp) * HW + h * 64 + wq * 4) = ov;
}

// ---------------------------------------------------------------------------
// Main kernel: r13 champion (33.2us) + ONE change: #pragma unroll 4 on the
// phase-A channel loop. Mechanism: at (512,2) the budget is ~128 VGPR but the
// compiler allocated only 56 for the plain loop (r11 measurement) -> ~2-deep
// load pipelining. unroll 4 makes 16 loads independent/hoistable (~+30 VGPR,
// still < 128, no forced spill - the r7 disaster was cap 64 < demand).
// Geometry unchanged: 512 blocks (b,h,w-half) x 512 thr, XCD decode bid&7 ->
// (batch, 32-row band) -> 2.4MB < 4MB per-XCD L2.
// ---------------------------------------------------------------------------
__global__ __launch_bounds__(512, 2) void selfattn_f16(const float* __restrict__ pwf,
                                                       float* __restrict__ out)
{
    const int bid = blockIdx.x;
    const int k   = bid & 7;
    const int seq = bid >> 3;            // 0..63
    const int b   = k >> 1;
    const int h   = (k & 1) * 32 + (seq >> 1);
    const int wbase = (seq & 1) * 32;    // w-half
    const int t = threadIdx.x;           // 0..511

    __shared__ float simRed[49][32];
    __shared__ __align__(16) h2 attnH[49][32];   // (a,a) packed
    __shared__ float redBuf[7][32];
    __shared__ float psumBuf[7][32];

    const float* pw = pwf + (size_t)b * (128 * HW);   // h2 elements viewed as float

    // ---------------- Phase A: sim[k][w] over 128 channel-pairs ----------------
    // thread = (w4: bits 0..2, cp: bits 3..5, dy: wave). iter i: pair = i*8+cp.
    {
        const int w4 = t & 7;
        const int cp = (t >> 3) & 7;
        const int dy = t >> 6;           // wave-uniform; dy==7 idle
        const int lw0 = w4 * 4;
        const int w0g = wbase + lw0;

        if (dy < 7) {
            float sim[7][4];
            #pragma unroll
            for (int dx = 0; dx < 7; ++dx)
                #pragma unroll
                for (int p = 0; p < 4; ++p) sim[dx][p] = 0.f;

            const int row = h + dy - 3;
            if (row >= 0 && row < Hdim) {
                const bool hasL = (w0g != 0);
                const bool hasR = (w0g != 60);
                const float* xr = pw + (size_t)cp * HW + row * 64;
                const float* xc = pw + (size_t)cp * HW + h   * 64;
                #pragma unroll 4
                for (int i = 0; i < 16; ++i) {
                    float fw[12];
                    if (hasL) {
                        f4 v = *(const f4*)(xr + w0g - 4);
                        fw[0]=v.x; fw[1]=v.y; fw[2]=v.z; fw[3]=v.w;
                    } else { fw[0]=0.f; fw[1]=0.f; fw[2]=0.f; fw[3]=0.f; }
                    {
                        f4 v = *(const f4*)(xr + w0g);
                        fw[4]=v.x; fw[5]=v.y; fw[6]=v.z; fw[7]=v.w;
                    }
                    if (hasR) {
                        f4 v = *(const f4*)(xr + w0g + 4);
                        fw[8]=v.x; fw[9]=v.y; fw[10]=v.z; fw[11]=v.w;
                    } else { fw[8]=0.f; fw[9]=0.f; fw[10]=0.f; fw[11]=0.f; }
                    f4 cen = *(const f4*)(xc + w0g);
                    h2 f2[12], cen2[4];
                    #pragma unroll
                    for (int j = 0; j < 12; ++j) f2[j] = __builtin_bit_cast(h2, fw[j]);
                    #pragma unroll
                    for (int p = 0; p < 4; ++p) cen2[p] = __builtin_bit_cast(h2, cen[p]);
                    #pragma unroll
                    for (int dx = 0; dx < 7; ++dx)
                        #pragma unroll
                        for (int p = 0; p < 4; ++p)
                            sim[dx][p] = fdot2f(cen2[p], f2[dx + p + 1], sim[dx][p]);
                    xr += 8 * HW;
                    xc += 8 * HW;
                }
            }
            // reduce over 8 channel partitions (lane bits 3..5)
            #pragma unroll
            for (int dx = 0; dx < 7; ++dx)
                #pragma unroll
                for (int p = 0; p < 4; ++p) {
                    float v = sim[dx][p];
                    v += __shfl_xor(v, 8);
                    v += __shfl_xor(v, 16);
                    v += __shfl_xor(v, 32);
                    sim[dx][p] = v;
                }
            if (cp == 0) {
                #pragma unroll
                for (int dx = 0; dx < 7; ++dx)
                    *(f4*)&simRed[dy * 7 + dx][lw0] = *(const f4*)sim[dx];
            }
        }
    }
    __syncthreads();

    // ---------------- Softmax over k=49; attn stored as (a,a) half2 ----------------
    {
        const int w  = t & 31;
        const int kc = t >> 5;    // 0..15; kc<7 active
        float sred[7], e[7];
        if (kc < 7) {
            float lmax = -3.0e38f;
            #pragma unroll
            for (int jj = 0; jj < 7; ++jj) {
                float s = simRed[kc * 7 + jj][w];
                sred[jj] = s;
                lmax = fmaxf(lmax, s);
            }
            redBuf[kc][w] = lmax;
        }
        __syncthreads();
        if (kc < 7) {
            float m = redBuf[0][w];
            #pragma unroll
            for (int q = 1; q < 7; ++q) m = fmaxf(m, redBuf[q][w]);
            float ps = 0.f;
            #pragma unroll
            for (int jj = 0; jj < 7; ++jj) {
                e[jj] = __expf(sred[jj] - m);
                ps += e[jj];
            }
            psumBuf[kc][w] = ps;
        }
        __syncthreads();
        if (kc < 7) {
            float l = psumBuf[0][w];
            #pragma unroll
            for (int q = 1; q < 7; ++q) l += psumBuf[q][w];
            float rinv = 1.0f / l;
            #pragma unroll
            for (int jj = 0; jj < 7; ++jj) {
                _Float16 ah = (_Float16)(e[jj] * rinv);
                h2 av; av[0] = ah; av[1] = ah;
                attnH[kc * 7 + jj][w] = av;
            }
        }
    }
    __syncthreads();

    // ---------------- Phase B: out via v_pk_fma_f16 ----------------
    // thread = (w4: bits 0..2, ci: bits 3..8) -> pairs 2ci,2ci+1 = channels 4ci..4ci+3
    {
        const int w4 = t & 7;
        const int ci = t >> 3;           // 0..63
        const int lw0 = w4 * 4;
        const int w0g = wbase + lw0;
        const bool hasL = (w0g != 0);
        const bool hasR = (w0g != 60);

        h2 acc2[2][4];
        #pragma unroll
        for (int pr = 0; pr < 2; ++pr)
            #pragma unroll
            for (int p = 0; p < 4; ++p) { acc2[pr][p][0] = (_Float16)0; acc2[pr][p][1] = (_Float16)0; }

        for (int dy = 0; dy < 7; ++dy) {
            const int row = h + dy - 3;
            if (row < 0 || row >= Hdim) continue;   // block-uniform
            h2 a2[7][4];
            #pragma unroll
            for (int dx = 0; dx < 7; ++dx) {
                f4 v = *(const f4*)&attnH[dy * 7 + dx][lw0];
                #pragma unroll
                for (int p = 0; p < 4; ++p) a2[dx][p] = __builtin_bit_cast(h2, v[p]);
            }
            #pragma unroll
            for (int pr = 0; pr < 2; ++pr) {
                const float* xr = pw + (size_t)(2 * ci + pr) * HW + row * 64;
                float fw[12];
                if (hasL) {
                    f4 v = *(const f4*)(xr + w0g - 4);
                    fw[0]=v.x; fw[1]=v.y; fw[2]=v.z; fw[3]=v.w;
                } else { fw[0]=0.f; fw[1]=0.f; fw[2]=0.f; fw[3]=0.f; }
                {
                    f4 v = *(const f4*)(xr + w0g);
                    fw[4]=v.x; fw[5]=v.y; fw[6]=v.z; fw[7]=v.w;
                }
                if (hasR) {
                    f4 v = *(const f4*)(xr + w0g + 4);
                    fw[8]=v.x; fw[9]=v.y; fw[10]=v.z; fw[11]=v.w;
                } else { fw[8]=0.f; fw[9]=0.f; fw[10]=0.f; fw[11]=0.f; }
                h2 f2[12];
                #pragma unroll
                for (int j = 0; j < 12; ++j) f2[j] = __builtin_bit_cast(h2, fw[j]);
                #pragma unroll
                for (int dx = 0; dx < 7; ++dx)
                    #pragma unroll
                    for (int p = 0; p < 4; ++p)
                        acc2[pr][p] += a2[dx][p] * f2[dx + p + 1];   // v_pk_fma_f16
            }
        }

        float* ob = out + (size_t)b * (Cdim * HW) + h * Wdim + w0g;
        #pragma unroll
        for (int pr = 0; pr < 2; ++pr) {
            f4 o0, o1;
            #pragma unroll
            for (int p = 0; p < 4; ++p) {
                o0[p] = (float)acc2[pr][p][0];
                o1[p] = (float)acc2[pr][p][1];
            }
            const int c0 = 4 * ci + 2 * pr;
            *(f4*)(ob + (size_t)c0 * HW)       = o0;
            *(f4*)(ob + (size_t)(c0 + 1) * HW) = o1;
        }
    }
}

// ---------------------------------------------------------------------------
// Fallback: r11 fp32 champion (40.0us) if ws is too small for the packed copy.
// ---------------------------------------------------------------------------
__global__ __launch_bounds__(512, 2) void selfattn_fb(const float* __restrict__ x,
                                                      float* __restrict__ out)
{
    const int bid = blockIdx.x;
    const int k   = bid & 7;
    const int seq = bid >> 3;
    const int b   = k >> 1;
    const int h   = (k & 1) * 32 + (seq >> 1);
    const int wbase = (seq & 1) * 32;
    const int t = threadIdx.x;

    __shared__ float simRed[49][32];
    __shared__ float attnBuf[49][32];
    __shared__ float redBuf[7][32];
    __shared__ float psumBuf[7][32];

    const float* xb = x + (size_t)b * (Cdim * HW);

    {
        const int w4 = t & 7;
        const int cp = (t >> 3) & 7;
        const int dy = t >> 6;
        const int lw0 = w4 * 4;
        const int w0g = wbase + lw0;

        if (dy < 7) {
            float sim[7][4];
            #pragma unroll
            for (int dx = 0; dx < 7; ++dx)
                #pragma unroll
                for (int p = 0; p < 4; ++p) sim[dx][p] = 0.f;

            const int row = h + dy - 3;
            if (row >= 0 && row < Hdim) {
                const bool hasL = (w0g != 0);
                const bool hasR = (w0g != 60);
                const float* xrA = xb + (size_t)cp * HW + row * Wdim;
                const float* xcA = xb + (size_t)cp * HW + h   * Wdim;
                const float* xrB = xrA + (size_t)128 * HW;
                const float* xcB = xcA + (size_t)128 * HW;
                #pragma unroll 2
                for (int i = 0; i < 16; ++i) {
                    float fA[12], fB[12];
                    if (hasL) {
                        f4 v = *(const f4*)(xrA + w0g - 4);
                        fA[0]=v.x; fA[1]=v.y; fA[2]=v.z; fA[3]=v.w;
                    } else { fA[0]=0.f; fA[1]=0.f; fA[2]=0.f; fA[3]=0.f; }
                    {
                        f4 v = *(const f4*)(xrA + w0g);
                        fA[4]=v.x; fA[5]=v.y; fA[6]=v.z; fA[7]=v.w;
                    }
                    if (hasR) {
                        f4 v = *(const f4*)(xrA + w0g + 4);
                        fA[8]=v.x; fA[9]=v.y; fA[10]=v.z; fA[11]=v.w;
                    } else { fA[8]=0.f; fA[9]=0.f; fA[10]=0.f; fA[11]=0.f; }
                    if (hasL) {
                        f4 v = *(const f4*)(xrB + w0g - 4);
                        fB[0]=v.x; fB[1]=v.y; fB[2]=v.z; fB[3]=v.w;
                    } else { fB[0]=0.f; fB[1]=0.f; fB[2]=0.f; fB[3]=0.f; }
                    {
                        f4 v = *(const f4*)(xrB + w0g);
                        fB[4]=v.x; fB[5]=v.y; fB[6]=v.z; fB[7]=v.w;
                    }
                    if (hasR) {
                        f4 v = *(const f4*)(xrB + w0g + 4);
                        fB[8]=v.x; fB[9]=v.y; fB[10]=v.z; fB[11]=v.w;
                    } else { fB[8]=0.f; fB[9]=0.f; fB[10]=0.f; fB[11]=0.f; }
                    f4 cenA = *(const f4*)(xcA + w0g);
                    f4 cenB = *(const f4*)(xcB + w0g);
                    #pragma unroll
                    for (int dx = 0; dx < 7; ++dx)
                        #pragma unroll
                        for (int p = 0; p < 4; ++p)
                            sim[dx][p] += cenA[p] * fA[dx + p + 1]
                                        + cenB[p] * fB[dx + p + 1];
                    xrA += 8 * HW;  xcA += 8 * HW;
                    xrB += 8 * HW;  xcB += 8 * HW;
                }
            }
            #pragma unroll
            for (int dx = 0; dx < 7; ++dx)
                #pragma unroll
                for (int p = 0; p < 4; ++p) {
                    float v = sim[dx][p];
                    v += __shfl_xor(v, 8);
                    v += __shfl_xor(v, 16);
                    v += __shfl_xor(v, 32);
                    sim[dx][p] = v;
                }
            if (cp == 0) {
                #pragma unroll
                for (int dx = 0; dx < 7; ++dx)
                    *(f4*)&simRed[dy * 7 + dx][lw0] = *(const f4*)sim[dx];
            }
        }
    }
    __syncthreads();

    {
        const int w  = t & 31;
        const int kc = t >> 5;
        float sred[7], e[7];
        if (kc < 7) {
            float lmax = -3.0e38f;
            #pragma unroll
            for (int jj = 0; jj < 7; ++jj) {
                float s = simRed[kc * 7 + jj][w];
                sred[jj] = s;
                lmax = fmaxf(lmax, s);
            }
            redBuf[kc][w] = lmax;
        }
        __syncthreads();
        if (kc < 7) {
            float m = redBuf[0][w];
            #pragma unroll
            for (int q = 1; q < 7; ++q) m = fmaxf(m, redBuf[q][w]);
            float ps = 0.f;
            #pragma unroll
            for (int jj = 0; jj < 7; ++jj) {
                e[jj] = __expf(sred[jj] - m);
                ps += e[jj];
            }
            psumBuf[kc][w] = ps;
        }
        __syncthreads();
        if (kc < 7) {
            float l = psumBuf[0][w];
            #pragma unroll
            for (int q = 1; q < 7; ++q) l += psumBuf[q][w];
            float rinv = 1.0f / l;
            #pragma unroll
            for (int jj = 0; jj < 7; ++jj)
                attnBuf[kc * 7 + jj][w] = e[jj] * rinv;
        }
    }
    __syncthreads();

    {
        const int w4 = t & 7;
        const int ci = t >> 3;
        const int lw0 = w4 * 4;
        const int w0g = wbase + lw0;
        const int c0 = ci * 4;
        const bool hasL = (w0g != 0);
        const bool hasR = (w0g != 60);

        float acc[4][4];
        #pragma unroll
        for (int ch = 0; ch < 4; ++ch)
            #pragma unroll
            for (int p = 0; p < 4; ++p) acc[ch][p] = 0.f;

        for (int dy = 0; dy < 7; ++dy) {
            const int row = h + dy - 3;
            if (row < 0 || row >= Hdim) continue;
            float a[7][4];
            #pragma unroll
            for (int dx = 0; dx < 7; ++dx) {
                f4 v = *(const f4*)&attnBuf[dy * 7 + dx][lw0];
                a[dx][0]=v.x; a[dx][1]=v.y; a[dx][2]=v.z; a[dx][3]=v.w;
            }
            const float* xr = xb + (size_t)c0 * HW + row * Wdim;
            #pragma unroll
            for (int ch = 0; ch < 4; ++ch) {
                float fw[12];
                if (hasL) {
                    f4 v = *(const f4*)(xr + w0g - 4);
                    fw[0]=v.x; fw[1]=v.y; fw[2]=v.z; fw[3]=v.w;
                } else { fw[0]=0.f; fw[1]=0.f; fw[2]=0.f; fw[3]=0.f; }
                {
                    f4 v = *(const f4*)(xr + w0g);
                    fw[4]=v.x; fw[5]=v.y; fw[6]=v.z; fw[7]=v.w;
                }
                if (hasR) {
                    f4 v = *(const f4*)(xr + w0g + 4);
                    fw[8]=v.x; fw[9]=v.y; fw[10]=v.z; fw[11]=v.w;
                } else { fw[8]=0.f; fw[9]=0.f; fw[10]=0.f; fw[11]=0.f; }
                #pragma unroll
                for (int dx = 0; dx < 7; ++dx)
                    #pragma unroll
                    for (int p = 0; p < 4; ++p)
                        acc[ch][p] += a[dx][p] * fw[dx + p + 1];
                xr += HW;
            }
        }

        float* ob = out + (size_t)b * (Cdim * HW) + h * Wdim + wbase;
        #pragma unroll
        for (int ch = 0; ch < 4; ++ch)
            *(f4*)(ob + (size_t)(c0 + ch) * HW + lw0) = *(const f4*)acc[ch];
    }
}

extern "C" void kernel_launch(void* const* d_in, const int* in_sizes, int n_in,
                              void* d_out, int out_size, void* d_ws, size_t ws_size,
                              hipStream_t stream)
{
    const float* x = (const float*)d_in[0];
    float* out = (float*)d_out;
    const size_t need = (size_t)4 * 128 * HW * 4;   // 8 MB packed half2
    if (ws_size >= need) {
        float* pw = (float*)d_ws;
        pack_kernel<<<dim3(1024), 512, 0, stream>>>(x, pw);
        selfattn_f16<<<dim3(512), 512, 0, stream>>>(pw, out);
    } else {
        selfattn_fb<<<dim3(512), 512, 0, stream>>>(x, out);
    }
}

// Round 19
// 32.773 us; speedup vs baseline: 1.0936x; 1.0229x over previous
//
#include <hip/hip_runtime.h>

typedef float f4 __attribute__((ext_vector_type(4)));
typedef _Float16 h2 __attribute__((ext_vector_type(2)));

#define Hdim 64
#define Wdim 64
#define Cdim 256
#define HW (Hdim * Wdim)

// v_dot2_f32_f16: d = a.x*b.x + a.y*b.y + c  (fp32 accumulate)
__device__ __forceinline__ float fdot2f(h2 a, h2 b, float c) {
#if __has_builtin(__builtin_amdgcn_fdot2)
    return __builtin_amdgcn_fdot2(a, b, c, false);
#else
    float d;
    asm("v_dot2_f32_f16 %0, %1, %2, %3" : "=v"(d) : "v"(a), "v"(b), "v"(c));
    return d;
#endif
}

// ---------------------------------------------------------------------------
// FINAL = r13 champion (33.2us, absmax 0.031 << 0.104 threshold).
// Journey: 79us (r2 naive-ish) -> 56 (XCD pinning: bid&7 owns a (batch,
// 32-row band), working set 2.4MB < 4MB per-XCD L2; FETCH 108MB->9MB)
// -> 40 (w-half split: 16 waves/CU) -> 33.2 (f16 pack: half bytes + half
// ops via v_dot2_f32_f16 / v_pk_fma_f16; fp32 sim accumulation).
// Falsified levers (r11-r18): MLP depth, LDS staging, w-quarter, h-pair
// sharing, phase split, shuffle windows, forced unroll — all neutral or
// negative. Register-allocator ledger: forced min-waves/EU budgets of
// 32/64 VGPR spill catastrophically (r6/r7); (512,2) with natural ~56-64
// demand is the stable point.
// ---------------------------------------------------------------------------

// Pack kernel: x fp32 [b][c][h][w] -> ws half2 [b][c/2][h][w] = {x[2cp],x[2cp+1]}
__global__ __launch_bounds__(512) void pack_kernel(const float* __restrict__ x,
                                                   float* __restrict__ pw)
{
    const int tid = blockIdx.x * 512 + threadIdx.x;   // 0..524287
    const int wq = tid & 15;
    const int h  = (tid >> 4) & 63;
    const int cp = (tid >> 10) & 127;
    const int b  = tid >> 17;
    const float* s0 = x + ((size_t)b * Cdim + 2 * cp) * HW + h * 64 + wq * 4;
    f4 v0 = *(const f4*)s0;
    f4 v1 = *(const f4*)(s0 + HW);
    f4 ov;
    #pragma unroll
    for (int p = 0; p < 4; ++p) {
        h2 o;
        o[0] = (_Float16)v0[p];
        o[1] = (_Float16)v1[p];
        ov[p] = __builtin_bit_cast(float, o);
    }
    *(f4*)(pw + ((size_t)b * 128 + cp) * HW + h * 64 + wq * 4) = ov;
}

// Main kernel: 512 blocks (b,h,w-half) x 512 thr on packed-f16 data.
__global__ __launch_bounds__(512, 2) void selfattn_f16(const float* __restrict__ pwf,
                                                       float* __restrict__ out)
{
    const int bid = blockIdx.x;
    const int k   = bid & 7;
    const int seq = bid >> 3;            // 0..63
    const int b   = k >> 1;
    const int h   = (k & 1) * 32 + (seq >> 1);
    const int wbase = (seq & 1) * 32;    // w-half
    const int t = threadIdx.x;           // 0..511

    __shared__ float simRed[49][32];
    __shared__ __align__(16) h2 attnH[49][32];   // (a,a) packed
    __shared__ float redBuf[7][32];
    __shared__ float psumBuf[7][32];

    const float* pw = pwf + (size_t)b * (128 * HW);   // h2 elements viewed as float

    // ---------------- Phase A: sim[k][w] over 128 channel-pairs ----------------
    // thread = (w4: bits 0..2, cp: bits 3..5, dy: wave). iter i: pair = i*8+cp.
    {
        const int w4 = t & 7;
        const int cp = (t >> 3) & 7;
        const int dy = t >> 6;           // wave-uniform; dy==7 idle
        const int lw0 = w4 * 4;
        const int w0g = wbase + lw0;

        if (dy < 7) {
            float sim[7][4];
            #pragma unroll
            for (int dx = 0; dx < 7; ++dx)
                #pragma unroll
                for (int p = 0; p < 4; ++p) sim[dx][p] = 0.f;

            const int row = h + dy - 3;
            if (row >= 0 && row < Hdim) {
                const bool hasL = (w0g != 0);
                const bool hasR = (w0g != 60);
                const float* xr = pw + (size_t)cp * HW + row * 64;
                const float* xc = pw + (size_t)cp * HW + h   * 64;
                for (int i = 0; i < 16; ++i) {
                    float fw[12];
                    if (hasL) {
                        f4 v = *(const f4*)(xr + w0g - 4);
                        fw[0]=v.x; fw[1]=v.y; fw[2]=v.z; fw[3]=v.w;
                    } else { fw[0]=0.f; fw[1]=0.f; fw[2]=0.f; fw[3]=0.f; }
                    {
                        f4 v = *(const f4*)(xr + w0g);
                        fw[4]=v.x; fw[5]=v.y; fw[6]=v.z; fw[7]=v.w;
                    }
                    if (hasR) {
                        f4 v = *(const f4*)(xr + w0g + 4);
                        fw[8]=v.x; fw[9]=v.y; fw[10]=v.z; fw[11]=v.w;
                    } else { fw[8]=0.f; fw[9]=0.f; fw[10]=0.f; fw[11]=0.f; }
                    f4 cen = *(const f4*)(xc + w0g);
                    h2 f2[12], cen2[4];
                    #pragma unroll
                    for (int j = 0; j < 12; ++j) f2[j] = __builtin_bit_cast(h2, fw[j]);
                    #pragma unroll
                    for (int p = 0; p < 4; ++p) cen2[p] = __builtin_bit_cast(h2, cen[p]);
                    #pragma unroll
                    for (int dx = 0; dx < 7; ++dx)
                        #pragma unroll
                        for (int p = 0; p < 4; ++p)
                            sim[dx][p] = fdot2f(cen2[p], f2[dx + p + 1], sim[dx][p]);
                    xr += 8 * HW;
                    xc += 8 * HW;
                }
            }
            // reduce over 8 channel partitions (lane bits 3..5)
            #pragma unroll
            for (int dx = 0; dx < 7; ++dx)
                #pragma unroll
                for (int p = 0; p < 4; ++p) {
                    float v = sim[dx][p];
                    v += __shfl_xor(v, 8);
                    v += __shfl_xor(v, 16);
                    v += __shfl_xor(v, 32);
                    sim[dx][p] = v;
                }
            if (cp == 0) {
                #pragma unroll
                for (int dx = 0; dx < 7; ++dx)
                    *(f4*)&simRed[dy * 7 + dx][lw0] = *(const f4*)sim[dx];
            }
        }
    }
    __syncthreads();

    // ---------------- Softmax over k=49; attn stored as (a,a) half2 ----------------
    {
        const int w  = t & 31;
        const int kc = t >> 5;    // 0..15; kc<7 active
        float sred[7], e[7];
        if (kc < 7) {
            float lmax = -3.0e38f;
            #pragma unroll
            for (int jj = 0; jj < 7; ++jj) {
                float s = simRed[kc * 7 + jj][w];
                sred[jj] = s;
                lmax = fmaxf(lmax, s);
            }
            redBuf[kc][w] = lmax;
        }
        __syncthreads();
        if (kc < 7) {
            float m = redBuf[0][w];
            #pragma unroll
            for (int q = 1; q < 7; ++q) m = fmaxf(m, redBuf[q][w]);
            float ps = 0.f;
            #pragma unroll
            for (int jj = 0; jj < 7; ++jj) {
                e[jj] = __expf(sred[jj] - m);
                ps += e[jj];
            }
            psumBuf[kc][w] = ps;
        }
        __syncthreads();
        if (kc < 7) {
            float l = psumBuf[0][w];
            #pragma unroll
            for (int q = 1; q < 7; ++q) l += psumBuf[q][w];
            float rinv = 1.0f / l;
            #pragma unroll
            for (int jj = 0; jj < 7; ++jj) {
                _Float16 ah = (_Float16)(e[jj] * rinv);
                h2 av; av[0] = ah; av[1] = ah;
                attnH[kc * 7 + jj][w] = av;
            }
        }
    }
    __syncthreads();

    // ---------------- Phase B: out via v_pk_fma_f16 ----------------
    // thread = (w4: bits 0..2, ci: bits 3..8) -> pairs 2ci,2ci+1 = channels 4ci..4ci+3
    {
        const int w4 = t & 7;
        const int ci = t >> 3;           // 0..63
        const int lw0 = w4 * 4;
        const int w0g = wbase + lw0;
        const bool hasL = (w0g != 0);
        const bool hasR = (w0g != 60);

        h2 acc2[2][4];
        #pragma unroll
        for (int pr = 0; pr < 2; ++pr)
            #pragma unroll
            for (int p = 0; p < 4; ++p) { acc2[pr][p][0] = (_Float16)0; acc2[pr][p][1] = (_Float16)0; }

        for (int dy = 0; dy < 7; ++dy) {
            const int row = h + dy - 3;
            if (row < 0 || row >= Hdim) continue;   // block-uniform
            h2 a2[7][4];
            #pragma unroll
            for (int dx = 0; dx < 7; ++dx) {
                f4 v = *(const f4*)&attnH[dy * 7 + dx][lw0];
                #pragma unroll
                for (int p = 0; p < 4; ++p) a2[dx][p] = __builtin_bit_cast(h2, v[p]);
            }
            #pragma unroll
            for (int pr = 0; pr < 2; ++pr) {
                const float* xr = pw + (size_t)(2 * ci + pr) * HW + row * 64;
                float fw[12];
                if (hasL) {
                    f4 v = *(const f4*)(xr + w0g - 4);
                    fw[0]=v.x; fw[1]=v.y; fw[2]=v.z; fw[3]=v.w;
                } else { fw[0]=0.f; fw[1]=0.f; fw[2]=0.f; fw[3]=0.f; }
                {
                    f4 v = *(const f4*)(xr + w0g);
                    fw[4]=v.x; fw[5]=v.y; fw[6]=v.z; fw[7]=v.w;
                }
                if (hasR) {
                    f4 v = *(const f4*)(xr + w0g + 4);
                    fw[8]=v.x; fw[9]=v.y; fw[10]=v.z; fw[11]=v.w;
                } else { fw[8]=0.f; fw[9]=0.f; fw[10]=0.f; fw[11]=0.f; }
                h2 f2[12];
                #pragma unroll
                for (int j = 0; j < 12; ++j) f2[j] = __builtin_bit_cast(h2, fw[j]);
                #pragma unroll
                for (int dx = 0; dx < 7; ++dx)
                    #pragma unroll
                    for (int p = 0; p < 4; ++p)
                        acc2[pr][p] += a2[dx][p] * f2[dx + p + 1];   // v_pk_fma_f16
            }
        }

        float* ob = out + (size_t)b * (Cdim * HW) + h * Wdim + w0g;
        #pragma unroll
        for (int pr = 0; pr < 2; ++pr) {
            f4 o0, o1;
            #pragma unroll
            for (int p = 0; p < 4; ++p) {
                o0[p] = (float)acc2[pr][p][0];
                o1[p] = (float)acc2[pr][p][1];
            }
            const int c0 = 4 * ci + 2 * pr;
            *(f4*)(ob + (size_t)c0 * HW)       = o0;
            *(f4*)(ob + (size_t)(c0 + 1) * HW) = o1;
        }
    }
}

// ---------------------------------------------------------------------------
// Fallback: r11 fp32 champion (40.0us) if ws is too small for the packed copy.
// ---------------------------------------------------------------------------
__global__ __launch_bounds__(512, 2) void selfattn_fb(const float* __restrict__ x,
                                                      float* __restrict__ out)
{
    const int bid = blockIdx.x;
    const int k   = bid & 7;
    const int seq = bid >> 3;
    const int b   = k >> 1;
    const int h   = (k & 1) * 32 + (seq >> 1);
    const int wbase = (seq & 1) * 32;
    const int t = threadIdx.x;

    __shared__ float simRed[49][32];
    __shared__ float attnBuf[49][32];
    __shared__ float redBuf[7][32];
    __shared__ float psumBuf[7][32];

    const float* xb = x + (size_t)b * (Cdim * HW);

    {
        const int w4 = t & 7;
        const int cp = (t >> 3) & 7;
        const int dy = t >> 6;
        const int lw0 = w4 * 4;
        const int w0g = wbase + lw0;

        if (dy < 7) {
            float sim[7][4];
            #pragma unroll
            for (int dx = 0; dx < 7; ++dx)
                #pragma unroll
                for (int p = 0; p < 4; ++p) sim[dx][p] = 0.f;

            const int row = h + dy - 3;
            if (row >= 0 && row < Hdim) {
                const bool hasL = (w0g != 0);
                const bool hasR = (w0g != 60);
                const float* xrA = xb + (size_t)cp * HW + row * Wdim;
                const float* xcA = xb + (size_t)cp * HW + h   * Wdim;
                const float* xrB = xrA + (size_t)128 * HW;
                const float* xcB = xcA + (size_t)128 * HW;
                #pragma unroll 2
                for (int i = 0; i < 16; ++i) {
                    float fA[12], fB[12];
                    if (hasL) {
                        f4 v = *(const f4*)(xrA + w0g - 4);
                        fA[0]=v.x; fA[1]=v.y; fA[2]=v.z; fA[3]=v.w;
                    } else { fA[0]=0.f; fA[1]=0.f; fA[2]=0.f; fA[3]=0.f; }
                    {
                        f4 v = *(const f4*)(xrA + w0g);
                        fA[4]=v.x; fA[5]=v.y; fA[6]=v.z; fA[7]=v.w;
                    }
                    if (hasR) {
                        f4 v = *(const f4*)(xrA + w0g + 4);
                        fA[8]=v.x; fA[9]=v.y; fA[10]=v.z; fA[11]=v.w;
                    } else { fA[8]=0.f; fA[9]=0.f; fA[10]=0.f; fA[11]=0.f; }
                    if (hasL) {
                        f4 v = *(const f4*)(xrB + w0g - 4);
                        fB[0]=v.x; fB[1]=v.y; fB[2]=v.z; fB[3]=v.w;
                    } else { fB[0]=0.f; fB[1]=0.f; fB[2]=0.f; fB[3]=0.f; }
                    {
                        f4 v = *(const f4*)(xrB + w0g);
                        fB[4]=v.x; fB[5]=v.y; fB[6]=v.z; fB[7]=v.w;
                    }
                    if (hasR) {
                        f4 v = *(const f4*)(xrB + w0g + 4);
                        fB[8]=v.x; fB[9]=v.y; fB[10]=v.z; fB[11]=v.w;
                    } else { fB[8]=0.f; fB[9]=0.f; fB[10]=0.f; fB[11]=0.f; }
                    f4 cenA = *(const f4*)(xcA + w0g);
                    f4 cenB = *(const f4*)(xcB + w0g);
                    #pragma unroll
                    for (int dx = 0; dx < 7; ++dx)
                        #pragma unroll
                        for (int p = 0; p < 4; ++p)
                            sim[dx][p] += cenA[p] * fA[dx + p + 1]
                                        + cenB[p] * fB[dx + p + 1];
                    xrA += 8 * HW;  xcA += 8 * HW;
                    xrB += 8 * HW;  xcB += 8 * HW;
                }
            }
            #pragma unroll
            for (int dx = 0; dx < 7; ++dx)
                #pragma unroll
                for (int p = 0; p < 4; ++p) {
                    float v = sim[dx][p];
                    v += __shfl_xor(v, 8);
                    v += __shfl_xor(v, 16);
                    v += __shfl_xor(v, 32);
                    sim[dx][p] = v;
                }
            if (cp == 0) {
                #pragma unroll
                for (int dx = 0; dx < 7; ++dx)
                    *(f4*)&simRed[dy * 7 + dx][lw0] = *(const f4*)sim[dx];
            }
        }
    }
    __syncthreads();

    {
        const int w  = t & 31;
        const int kc = t >> 5;
        float sred[7], e[7];
        if (kc < 7) {
            float lmax = -3.0e38f;
            #pragma unroll
            for (int jj = 0; jj < 7; ++jj) {
                float s = simRed[kc * 7 + jj][w];
                sred[jj] = s;
                lmax = fmaxf(lmax, s);
            }
            redBuf[kc][w] = lmax;
        }
        __syncthreads();
        if (kc < 7) {
            float m = redBuf[0][w];
            #pragma unroll
            for (int q = 1; q < 7; ++q) m = fmaxf(m, redBuf[q][w]);
            float ps = 0.f;
            #pragma unroll
            for (int jj = 0; jj < 7; ++jj) {
                e[jj] = __expf(sred[jj] - m);
                ps += e[jj];
            }
            psumBuf[kc][w] = ps;
        }
        __syncthreads();
        if (kc < 7) {
            float l = psumBuf[0][w];
            #pragma unroll
            for (int q = 1; q < 7; ++q) l += psumBuf[q][w];
            float rinv = 1.0f / l;
            #pragma unroll
            for (int jj = 0; jj < 7; ++jj)
                attnBuf[kc * 7 + jj][w] = e[jj] * rinv;
        }
    }
    __syncthreads();

    {
        const int w4 = t & 7;
        const int ci = t >> 3;
        const int lw0 = w4 * 4;
        const int w0g = wbase + lw0;
        const int c0 = ci * 4;
        const bool hasL = (w0g != 0);
        const bool hasR = (w0g != 60);

        float acc[4][4];
        #pragma unroll
        for (int ch = 0; ch < 4; ++ch)
            #pragma unroll
            for (int p = 0; p < 4; ++p) acc[ch][p] = 0.f;

        for (int dy = 0; dy < 7; ++dy) {
            const int row = h + dy - 3;
            if (row < 0 || row >= Hdim) continue;
            float a[7][4];
            #pragma unroll
            for (int dx = 0; dx < 7; ++dx) {
                f4 v = *(const f4*)&attnBuf[dy * 7 + dx][lw0];
                a[dx][0]=v.x; a[dx][1]=v.y; a[dx][2]=v.z; a[dx][3]=v.w;
            }
            const float* xr = xb + (size_t)c0 * HW + row * Wdim;
            #pragma unroll
            for (int ch = 0; ch < 4; ++ch) {
                float fw[12];
                if (hasL) {
                    f4 v = *(const f4*)(xr + w0g - 4);
                    fw[0]=v.x; fw[1]=v.y; fw[2]=v.z; fw[3]=v.w;
                } else { fw[0]=0.f; fw[1]=0.f; fw[2]=0.f; fw[3]=0.f; }
                {
                    f4 v = *(const f4*)(xr + w0g);
                    fw[4]=v.x; fw[5]=v.y; fw[6]=v.z; fw[7]=v.w;
                }
                if (hasR) {
                    f4 v = *(const f4*)(xr + w0g + 4);
                    fw[8]=v.x; fw[9]=v.y; fw[10]=v.z; fw[11]=v.w;
                } else { fw[8]=0.f; fw[9]=0.f; fw[10]=0.f; fw[11]=0.f; }
                #pragma unroll
                for (int dx = 0; dx < 7; ++dx)
                    #pragma unroll
                    for (int p = 0; p < 4; ++p)
                        acc[ch][p] += a[dx][p] * fw[dx + p + 1];
                xr += HW;
            }
        }

        float* ob = out + (size_t)b * (Cdim * HW) + h * Wdim + wbase;
        #pragma unroll
        for (int ch = 0; ch < 4; ++ch)
            *(f4*)(ob + (size_t)(c0 + ch) * HW + lw0) = *(const f4*)acc[ch];
    }
}

extern "C" void kernel_launch(void* const* d_in, const int* in_sizes, int n_in,
                              void* d_out, int out_size, void* d_ws, size_t ws_size,
                              hipStream_t stream)
{
    const float* x = (const float*)d_in[0];
    float* out = (float*)d_out;
    const size_t need = (size_t)4 * 128 * HW * 4;   // 8 MB packed half2
    if (ws_size >= need) {
        float* pw = (float*)d_ws;
        pack_kernel<<<dim3(1024), 512, 0, stream>>>(x, pw);
        selfattn_f16<<<dim3(512), 512, 0, stream>>>(pw, out);
    } else {
        selfattn_fb<<<dim3(512), 512, 0, stream>>>(x, out);
    }
}